// Round 8
// baseline (132.221 us; speedup 1.0000x reference)
//
#include <hip/hip_runtime.h>

// S = J^T K per (p,b); att = softmax over j (per k-column); out = V * att.
// 64 batches; C=64; N=1024. fp32 in/out.
//
// v6 = v5 structure with the exp hazard fixed.
//  - v5 FAILED (absmax 0.107): raw inline-asm v_exp_f32 omitted the CDNA
//    trans-op wait state the compiler normally inserts -> sporadic stale-reg
//    reads. Fix: exp2f() (still a single v_exp_f32; K is pre-scaled by log2e).
//  - 512-thread WGs (8 waves), grid 512 (KTW=128): 16 waves/CU = 4 waves/SIMD
//    (v4 had 2). Per wave: 12+4 MFMA, 8 exps, 16-reg U. Latency chains halve.
//  - __launch_bounds__(512,4): targets the 128-VGPR cap for 2 WG/CU residency
//    (est. demand ~107). Spill tripwire: VGPR_Count/WRITE_SIZE in post-mortem.
//  - P cross-wave (wj-pair) per k-group; U has no cross-wave reduce; Z gets a
//    tiny LDS exchange in the epilogue.
//  - v4-proven strides (SJK 76, SV/SP 36), trunc hi/lo split, bf16 P/V path.

typedef short bf16x8 __attribute__((ext_vector_type(8)));
typedef short bf16x4 __attribute__((ext_vector_type(4)));
typedef float f32x4  __attribute__((ext_vector_type(4)));

#define NTOK 1024
#define CH   64
#define KTW  128   // k-columns per WG
#define JTILE 32   // j-rows per iteration
#define NIT  (NTOK / JTILE)
#define SJK  76    // stride (shorts) for transposed J/K tiles
#define SV   36    // stride for V tiles
#define SP   36    // stride for P tiles
#define LOG2E 1.4426950408889634f

__device__ __forceinline__ unsigned short f2bf_rne(float x) {
  unsigned int u = __float_as_uint(x);
  u += 0x7FFFu + ((u >> 16) & 1u);
  return (unsigned short)(u >> 16);
}

#define MFMA(a,b,c) __builtin_amdgcn_mfma_f32_16x16x32_bf16((a),(b),(c),0,0,0)

__global__ __launch_bounds__(512, 4) void attn_v6(
    const float* __restrict__ Kg, const float* __restrict__ Jg,
    const float* __restrict__ Vg, float* __restrict__ Og) {
  // LDS: K 38912 + J 19456 + V 9216 + P 9216 = 76,800 B (2 WG/CU)
  __shared__ unsigned short KhS[KTW][SJK];
  __shared__ unsigned short KlS[KTW][SJK];
  __shared__ unsigned short JhS[2][JTILE][SJK];
  __shared__ unsigned short JlS[2][JTILE][SJK];
  __shared__ unsigned short VtS[2][CH][SV];
  __shared__ unsigned short PtS[4][JTILE][SP];   // per k-group [k32][j32]

  const int tid  = threadIdx.x;
  const int lane = tid & 63;
  const int wave = tid >> 6;     // 0..7
  const int wk   = wave & 3;     // k-group (32 k each)
  const int wj   = wave >> 2;    // j-half (16 j each) / c-half for PV
  const int l15  = lane & 15;
  const int l4   = lane >> 4;

  const int bid   = blockIdx.x;
  const int batch = bid & 63;    // bid%8 == batch%8 -> same-batch WGs share an XCD
  const int ktile = bid >> 6;    // 0..7
  const int k0    = ktile * KTW;
  const size_t base = (size_t)batch * (CH * NTOK);
  const float* Kp = Kg + base;
  const float* Jp = Jg + base;
  const float* Vp = Vg + base;
  float*       Op = Og + base;

  // staging geometry (512 threads):
  // J: j = tid&31, c-quad = (tid>>5)*4  (16 quads x 32 j = 512 tasks)
  const int jJ  = tid & 31;
  const int cq  = tid >> 5;                 // 0..15
  const float* srcJ = Jp + (size_t)(cq * 4) * NTOK + jJ;
  // V: row c0, 4-wide col quad (64 c x 8 quads = 512 tasks)
  const int c0  = tid >> 3;
  const int jq0 = tid & 7;
  const float* srcV = Vp + (size_t)c0 * NTOK + jq0 * 4;

  float  jr[4];
  float4 vr;

  auto issueJV = [&](int j0) {
    #pragma unroll
    for (int r = 0; r < 4; ++r) jr[r] = srcJ[(size_t)r * NTOK + j0];
    vr = *(const float4*)(srcV + j0);
  };
  auto stageJV = [&](int buf) {
    bf16x4 hv, lv;
    #pragma unroll
    for (int r = 0; r < 4; ++r) {
      unsigned int u = __float_as_uint(jr[r]);
      hv[r] = (short)(u >> 16);
      float hf = __uint_as_float(u & 0xFFFF0000u);
      lv[r] = (short)(__float_as_uint(jr[r] - hf) >> 16);
    }
    *(bf16x4*)&JhS[buf][jJ][cq * 4] = hv;
    *(bf16x4*)&JlS[buf][jJ][cq * 4] = lv;
    bf16x4 w;
    w[0] = (short)f2bf_rne(vr.x); w[1] = (short)f2bf_rne(vr.y);
    w[2] = (short)f2bf_rne(vr.z); w[3] = (short)f2bf_rne(vr.w);
    *(bf16x4*)&VtS[buf][c0][jq0 * 4] = w;
  };

  // ---- prologue: iter-0 J/V in flight under K staging ----
  issueJV(0);

  // stage K (one-time): transpose [c][k]->[k][c], scale by log2e, hi/lo split
  {
    const int kk   = tid & 127;
    const int oct4 = tid >> 7;              // 0..3, 16 c each
    const float* srcK = Kp + (size_t)(oct4 * 16) * NTOK + k0 + kk;
    bf16x8 hv0, lv0, hv1, lv1;
    #pragma unroll
    for (int r = 0; r < 8; ++r) {
      float v = srcK[(size_t)r * NTOK] * LOG2E;
      unsigned int u = __float_as_uint(v);
      hv0[r] = (short)(u >> 16);
      float hf = __uint_as_float(u & 0xFFFF0000u);
      lv0[r] = (short)(__float_as_uint(v - hf) >> 16);
    }
    #pragma unroll
    for (int r = 0; r < 8; ++r) {
      float v = srcK[(size_t)(8 + r) * NTOK] * LOG2E;
      unsigned int u = __float_as_uint(v);
      hv1[r] = (short)(u >> 16);
      float hf = __uint_as_float(u & 0xFFFF0000u);
      lv1[r] = (short)(__float_as_uint(v - hf) >> 16);
    }
    *(bf16x8*)&KhS[kk][oct4 * 16]     = hv0;
    *(bf16x8*)&KhS[kk][oct4 * 16 + 8] = hv1;
    *(bf16x8*)&KlS[kk][oct4 * 16]     = lv0;
    *(bf16x8*)&KlS[kk][oct4 * 16 + 8] = lv1;
  }
  __syncthreads();

  // hoist this wave's K fragments (loop-invariant); pin best-effort
  bf16x8 kbh[2][2], kbl[2][2];     // [ks][cd]
  #pragma unroll
  for (int ks = 0; ks < 2; ++ks)
    #pragma unroll
    for (int cd = 0; cd < 2; ++cd) {
      kbh[ks][cd] = *(const bf16x8*)&KhS[wk * 32 + ks * 16 + l15][cd * 32 + l4 * 8];
      kbl[ks][cd] = *(const bf16x8*)&KlS[wk * 32 + ks * 16 + l15][cd * 32 + l4 * 8];
      asm volatile("" : "+v"(kbh[ks][cd]), "+v"(kbl[ks][cd]));
    }

  stageJV(0);
  __syncthreads();

  f32x4 U[2][2];   // [ct (c-16 within wj c-half)][ks]
  #pragma unroll
  for (int a = 0; a < 2; ++a)
    #pragma unroll
    for (int b = 0; b < 2; ++b) U[a][b] = (f32x4){0.f, 0.f, 0.f, 0.f};
  float zacc0 = 0.f, zacc1 = 0.f;

  int cur = 0;
  #pragma unroll 1
  for (int it = 0; it < NIT; ++it) {
    if (it + 1 < NIT) issueJV((it + 1) * JTILE);   // in flight under compute

    // ---- QK^T for this wave's (j-half, k-group): 12 MFMA ----
    f32x4 S[2];    // [ks]; j = wj*16 + l4*4 + r, k = wk*32 + ks*16 + l15
    S[0] = (f32x4){0.f, 0.f, 0.f, 0.f};
    S[1] = (f32x4){0.f, 0.f, 0.f, 0.f};
    __builtin_amdgcn_s_setprio(1);
    #pragma unroll
    for (int cd = 0; cd < 2; ++cd) {
      const int co = cd * 32 + l4 * 8;
      bf16x8 ah = *(const bf16x8*)&JhS[cur][wj * 16 + l15][co];
      bf16x8 al = *(const bf16x8*)&JlS[cur][wj * 16 + l15][co];
      #pragma unroll
      for (int ks = 0; ks < 2; ++ks) {
        S[ks] = MFMA(ah, kbh[ks][cd], S[ks]);
        S[ks] = MFMA(ah, kbl[ks][cd], S[ks]);
        S[ks] = MFMA(al, kbh[ks][cd], S[ks]);
      }
    }
    __builtin_amdgcn_s_setprio(0);

    // ---- P = 2^S (K pre-scaled by log2e), Z partials, pack, stash ----
    #pragma unroll
    for (int ks = 0; ks < 2; ++ks) {
      f32x4 s = S[ks];
      float e0 = exp2f(s[0]);
      float e1 = exp2f(s[1]);
      float e2 = exp2f(s[2]);
      float e3 = exp2f(s[3]);
      if (ks == 0) zacc0 += (e0 + e1) + (e2 + e3);
      else         zacc1 += (e0 + e1) + (e2 + e3);
      bf16x4 pv;
      pv[0] = (short)f2bf_rne(e0); pv[1] = (short)f2bf_rne(e1);
      pv[2] = (short)f2bf_rne(e2); pv[3] = (short)f2bf_rne(e3);
      *(bf16x4*)&PtS[wk][ks * 16 + l15][wj * 16 + l4 * 4] = pv;
    }
    __syncthreads();   // P halves visible across the wj pair

    // ---- PV: U[c-half wj][k-group wk] += V * P (full j inside MFMA) ----
    bf16x8 pb0 = *(const bf16x8*)&PtS[wk][l15][l4 * 8];
    bf16x8 pb1 = *(const bf16x8*)&PtS[wk][16 + l15][l4 * 8];
    __builtin_amdgcn_s_setprio(1);
    #pragma unroll
    for (int ct = 0; ct < 2; ++ct) {
      bf16x8 av = *(const bf16x8*)&VtS[cur][wj * 32 + ct * 16 + l15][l4 * 8];
      U[ct][0] = MFMA(av, pb0, U[ct][0]);
      U[ct][1] = MFMA(av, pb1, U[ct][1]);
    }
    __builtin_amdgcn_s_setprio(0);

    // ---- stage next tile into the other buffer ----
    if (it + 1 < NIT) stageJV(cur ^ 1);
    __syncthreads();   // staging done + P reads done before next iter reuses
    cur ^= 1;
  }

  // ---- epilogue: Z within wave, then across the wj pair via LDS ----
  float z0 = zacc0; z0 += __shfl_xor(z0, 16); z0 += __shfl_xor(z0, 32);
  float z1 = zacc1; z1 += __shfl_xor(z1, 16); z1 += __shfl_xor(z1, 32);

  float* ZL = (float*)&PtS[0][0][0];   // reuse P region: [4 wk][2 wj][32 k]
  if (lane < 16) {
    ZL[(wk * 2 + wj) * 32 + l15]      = z0;
    ZL[(wk * 2 + wj) * 32 + 16 + l15] = z1;
  }
  __syncthreads();
  z0 += ZL[(wk * 2 + (wj ^ 1)) * 32 + l15];
  z1 += ZL[(wk * 2 + (wj ^ 1)) * 32 + 16 + l15];
  const float rz0 = 1.0f / z0;
  const float rz1 = 1.0f / z1;

  const int kbase = k0 + wk * 32;
  #pragma unroll
  for (int ct = 0; ct < 2; ++ct)
    #pragma unroll
    for (int r = 0; r < 4; ++r) {
      int c = wj * 32 + ct * 16 + l4 * 4 + r;
      Op[(size_t)c * NTOK + kbase + l15]      = U[ct][0][r] * rz0;
      Op[(size_t)c * NTOK + kbase + 16 + l15] = U[ct][1][r] * rz1;
    }
}

extern "C" void kernel_launch(void* const* d_in, const int* in_sizes, int n_in,
                              void* d_out, int out_size, void* d_ws, size_t ws_size,
                              hipStream_t stream) {
  const float* Kg = (const float*)d_in[0];
  const float* Jg = (const float*)d_in[1];
  const float* Vg = (const float*)d_in[2];
  float* Og = (float*)d_out;
  // 8 ktiles x 64 batches; bid = ktile*64 + batch keeps a batch's 8 WGs on one XCD.
  attn_v6<<<dim3(512), dim3(512), 0, stream>>>(Kg, Jg, Vg, Og);
}